// Round 12
// baseline (387.403 us; speedup 1.0000x reference)
//
#include <hip/hip_runtime.h>
#include <hip/hip_bf16.h>
#include <math.h>

// Problem constants: x [8,256,64,64] fp32, N = 4096, C = 256, Cqk = 32.
#define B_   8
#define C_   256
#define N_   4096
// 1/sqrt(32) * log2(e): scores computed directly in log2 space -> exp2 only.
#define QSCALE_L2E 0.2550541451582815f
#define DEFER_THR  11.5f   // defer-max threshold in log2 units (~8 nats)

typedef __attribute__((ext_vector_type(8))) short bf16x8;   // 8 bf16 = 4 VGPRs
typedef __attribute__((ext_vector_type(4))) float f32x4;

__device__ __forceinline__ unsigned short bfu(float f) {
    __hip_bfloat16 h = __float2bfloat16(f);
    return __builtin_bit_cast(unsigned short, h);
}
// v_cvt_pk_bf16_f32: lo -> D[15:0], hi -> D[31:16] (single VALU op)
__device__ __forceinline__ unsigned cvtpk(float lo, float hi) {
    unsigned r;
    asm("v_cvt_pk_bf16_f32 %0, %1, %2" : "=v"(r) : "v"(lo), "v"(hi));
    return r;
}

// ---------------------------------------------------------------------------
// Kernel 0: one-time W -> bf16 prep. wbf layout: Wq[32*256] | Wk | Wv[256*256].
// ---------------------------------------------------------------------------
__global__ __launch_bounds__(256) void w_prep(
    const float* __restrict__ Wq, const float* __restrict__ Wk,
    const float* __restrict__ Wv, unsigned short* __restrict__ wbf)
{
    const int i = blockIdx.x * 256 + threadIdx.x;
    const int off = i * 4;
    float4 f;
    if (off < 32 * C_)            f = *reinterpret_cast<const float4*>(Wq + off);
    else if (off < 64 * C_)       f = *reinterpret_cast<const float4*>(Wk + off - 32 * C_);
    else                          f = *reinterpret_cast<const float4*>(Wv + off - 64 * C_);
    ushort4 u;
    u.x = bfu(f.x); u.y = bfu(f.y); u.z = bfu(f.z); u.w = bfu(f.w);
    *reinterpret_cast<ushort4*>(wbf + off) = u;
}

// ---------------------------------------------------------------------------
// Kernel 1: QKV projection via MFMA (unchanged since round 6).
// Outputs: q,k [b][n][32] bf16 (q pre-scaled by QSCALE_L2E), v [b][c][n] bf16.
// ---------------------------------------------------------------------------
__global__ __launch_bounds__(256, 2) void qkv_proj_mfma(
    const float* __restrict__ x, const unsigned short* __restrict__ wbf,
    const float* __restrict__ bq, const float* __restrict__ bk,
    const float* __restrict__ bv,
    unsigned short* __restrict__ q, unsigned short* __restrict__ k,
    unsigned short* __restrict__ v)
{
    const int b = blockIdx.y, n0 = blockIdx.x * 64;
    const int t = threadIdx.x;
    const int w = t >> 6, l = t & 63;
    const int li = l & 15, g = l >> 4;

    __shared__ unsigned short xT[64 * 256];     // 32 KB; reused as vS[256][64]
    __shared__ unsigned short qkS[2 * 64 * 32]; // 8 KB

    {
        const int n = t & 63;
        const int cq0 = t >> 6;
        const float* xb = x + ((size_t)b * C_) * N_ + n0 + n;
        #pragma unroll 4
        for (int s = 0; s < 16; ++s) {
            const int cq = cq0 + 4 * s;
            const float f0 = xb[(size_t)(cq * 4 + 0) * N_];
            const float f1 = xb[(size_t)(cq * 4 + 1) * N_];
            const float f2 = xb[(size_t)(cq * 4 + 2) * N_];
            const float f3 = xb[(size_t)(cq * 4 + 3) * N_];
            ushort4 pk;
            pk.x = bfu(f0); pk.y = bfu(f1); pk.z = bfu(f2); pk.w = bfu(f3);
            const int byte = n * 512 + (((cq >> 1) ^ (n & 7)) << 4) + (cq & 1) * 8;
            *reinterpret_cast<ushort4*>(reinterpret_cast<char*>(xT) + byte) = pk;
        }
    }
    __syncthreads();

    const unsigned short* wq_bf = wbf;
    const unsigned short* wk_bf = wbf + 32 * C_;
    const unsigned short* wv_bf = wbf + 64 * C_;

    const unsigned short* wqk_bf = (w < 2) ? wq_bf : wk_bf;
    const float* bqk = (w < 2) ? bq : bk;
    const float qscl = (w < 2) ? QSCALE_L2E : 1.0f;
    const int mt0 = (w & 1) * 2;
    const int ov0 = w * 64;

    f32x4 accv[4][4];
    f32x4 accq[2][2];
    const f32x4 z4 = {0.f, 0.f, 0.f, 0.f};
    #pragma unroll
    for (int a = 0; a < 4; ++a)
        #pragma unroll
        for (int c2 = 0; c2 < 4; ++c2) accv[a][c2] = z4;
    #pragma unroll
    for (int a = 0; a < 2; ++a)
        #pragma unroll
        for (int c2 = 0; c2 < 2; ++c2) accq[a][c2] = z4;

    #pragma unroll 2
    for (int kk = 0; kk < 8; ++kk) {
        bf16x8 xf[4];
        #pragma unroll
        for (int nt = 0; nt < 4; ++nt) {
            const int row = nt * 16 + li;
            const int byte = row * 512 + (((kk * 4 + g) ^ (row & 7)) << 4);
            xf[nt] = *reinterpret_cast<const bf16x8*>(
                reinterpret_cast<const char*>(xT) + byte);
        }
        #pragma unroll
        for (int ot = 0; ot < 4; ++ot) {
            const bf16x8 wV = *reinterpret_cast<const bf16x8*>(
                wv_bf + (size_t)(ov0 + ot * 16 + li) * C_ + kk * 32 + g * 8);
            #pragma unroll
            for (int nt = 0; nt < 4; ++nt)
                accv[nt][ot] = __builtin_amdgcn_mfma_f32_16x16x32_bf16(
                    xf[nt], wV, accv[nt][ot], 0, 0, 0);
        }
        #pragma unroll
        for (int ot = 0; ot < 2; ++ot) {
            const bf16x8 wA = *reinterpret_cast<const bf16x8*>(
                wqk_bf + (size_t)(ot * 16 + li) * C_ + kk * 32 + g * 8);
            #pragma unroll
            for (int m2 = 0; m2 < 2; ++m2)
                accq[ot][m2] = __builtin_amdgcn_mfma_f32_16x16x32_bf16(
                    wA, xf[mt0 + m2], accq[ot][m2], 0, 0, 0);
        }
    }

    __syncthreads();   // xT reads done: reuse as vS

    {
        const int qk = (w < 2) ? 0 : 1;
        #pragma unroll
        for (int ot = 0; ot < 2; ++ot) {
            const int d0 = ot * 16 + 4 * g;
            const float4 b4 = *reinterpret_cast<const float4*>(bqk + d0);
            const int slot = ot * 4 + g;
            #pragma unroll
            for (int m2 = 0; m2 < 2; ++m2) {
                const int n = (mt0 + m2) * 16 + li;
                ushort4 s4;
                s4.x = bfu((accq[ot][m2][0] + b4.x) * qscl);
                s4.y = bfu((accq[ot][m2][1] + b4.y) * qscl);
                s4.z = bfu((accq[ot][m2][2] + b4.z) * qscl);
                s4.w = bfu((accq[ot][m2][3] + b4.w) * qscl);
                const int byte = qk * 4096 + n * 64 + ((slot ^ (n & 7)) << 3);
                *reinterpret_cast<ushort4*>(reinterpret_cast<char*>(qkS) + byte) = s4;
            }
        }
    }
    {
        #pragma unroll
        for (int ot = 0; ot < 4; ++ot) {
            const int o = ov0 + ot * 16 + li;
            const float bias = bv[o];
            #pragma unroll
            for (int nt = 0; nt < 4; ++nt) {
                ushort4 s4;
                s4.x = bfu(accv[nt][ot][0] + bias);
                s4.y = bfu(accv[nt][ot][1] + bias);
                s4.z = bfu(accv[nt][ot][2] + bias);
                s4.w = bfu(accv[nt][ot][3] + bias);
                const int slot = nt * 4 + g;
                const int byte = o * 128 + ((slot ^ (o & 7)) << 3);
                *reinterpret_cast<ushort4*>(reinterpret_cast<char*>(xT) + byte) = s4;
            }
        }
    }
    __syncthreads();

    {
        const char* qks = reinterpret_cast<const char*>(qkS);
        #pragma unroll
        for (int qk = 0; qk < 2; ++qk) {
            const int n = t >> 2, s2 = (t & 3) * 2;
            const int byteA = qk * 4096 + n * 64 + (((s2    ) ^ (n & 7)) << 3);
            const int byteB = qk * 4096 + n * 64 + (((s2 + 1) ^ (n & 7)) << 3);
            const uint2 lo = *reinterpret_cast<const uint2*>(qks + byteA);
            const uint2 hi = *reinterpret_cast<const uint2*>(qks + byteB);
            uint4 val = make_uint4(lo.x, lo.y, hi.x, hi.y);
            unsigned short* dst = (qk == 0) ? q : k;
            *reinterpret_cast<uint4*>(dst + ((size_t)b * N_ + n0) * 32 + t * 8) = val;
        }
    }
    {
        const char* vs = reinterpret_cast<const char*>(xT);
        #pragma unroll
        for (int p2 = 0; p2 < 8; ++p2) {
            const int o = p2 * 32 + (t >> 3);
            const int s2 = (t & 7) * 2;
            const int byteA = o * 128 + (((s2    ) ^ (o & 7)) << 3);
            const int byteB = o * 128 + (((s2 + 1) ^ (o & 7)) << 3);
            const uint2 lo = *reinterpret_cast<const uint2*>(vs + byteA);
            const uint2 hi = *reinterpret_cast<const uint2*>(vs + byteB);
            uint4 val = make_uint4(lo.x, lo.y, hi.x, hi.y);
            *reinterpret_cast<uint4*>(v + ((size_t)b * C_ + o) * N_ + n0 + (t & 7) * 8) = val;
        }
    }
}

// ---------------------------------------------------------------------------
// Kernel 2: flash attention, 32 q/wave + j-split for TLP. grid 256 (b = id&7
// -> XCD-local, i0 = (id>>3)*128), 512 threads (8 waves), 1 block/CU =
// 2 waves/SIMD. Wave (QS = w&3, JH = w>>2): 32 queries (two MFMA groups A/B
// sharing every K/V A-frag read) x its 64-j half of each 128-j staging tile.
// Per-CU LDS port traffic = HALF of round 10 at round 10's occupancy (the
// two measured requirements). O/m/l are per-(QS,JH) partials, merged once at
// the epilogue (m/l via small LDS; O halves exchanged through the retired V
// buffer; each wave finalizes 128 c x 32 q). T14 staging, counted waits.
// LDS = 16 (K dbuf) + 128 (V dbuf) + 2 (m/l) = 146 KB.
// ---------------------------------------------------------------------------
__global__ __launch_bounds__(512, 2) void attn_mfma(
    const unsigned short* __restrict__ q, const unsigned short* __restrict__ k,
    const unsigned short* __restrict__ v,
    const float* __restrict__ x, const float* __restrict__ gamma,
    float* __restrict__ out)
{
    const int id = blockIdx.x;
    const int b = id & 7;                 // batch == XCD
    const int i0 = (id >> 3) * 128;
    const int t = threadIdx.x;
    const int w = t >> 6, l = t & 63;
    const int li = l & 15, g = l >> 4;
    const int QS = w & 3;                 // query slice: 32 queries
    const int JH = w >> 2;                // j-half of the 128-j tile

    __shared__ unsigned short kT[2][128 * 32];              // 16 KB dbuf K
    __shared__ __align__(16) unsigned short vT[2][2][256 * 64];  // 128 KB dbuf V (2 j-subtiles)
    __shared__ float m_x[4][2][2][16];                      // [qs][jh][grp][li]
    __shared__ float l_x[4][2][2][16];

    const unsigned short* qb = q + (size_t)b * N_ * 32;
    const unsigned short* kb = k + (size_t)b * N_ * 32;
    const unsigned short* vb = v + ((size_t)b * C_) * N_;

    // Q B-frags for own 32 queries: group A = i0+QS*32+li, group B = A+16
    const bf16x8 qfA = *reinterpret_cast<const bf16x8*>(
        qb + (size_t)(i0 + QS * 32 + li) * 32 + g * 8);
    const bf16x8 qfB = *reinterpret_cast<const bf16x8*>(
        qb + (size_t)(i0 + QS * 32 + 16 + li) * 32 + g * 8);

    f32x4 accA[16], accB[16];   // O^T partial (own j-half): c = ct*16+4g+r
    const f32x4 z4 = {0.f, 0.f, 0.f, 0.f};
    #pragma unroll
    for (int a = 0; a < 16; ++a) { accA[a] = z4; accB[a] = z4; }

    float m_runA = -3.0e38f, m_runB = -3.0e38f;
    float l_pA = 0.f, l_pB = 0.f;

    // ---- K staging (128-row tile, r7-verified): tt within 256, hh = half ----
    const int tt = t & 255, hh = t >> 8;
    const int jr = tt >> 2, sl = tt & 3;
    const int jt_s = jr >> 4, gg = (jr >> 2) & 3, rr = jr & 3;
    const int jloc = (jt_s >> 1) * 32 + (jt_s & 1) * 4 + gg * 8 + rr;
    const int s_src = sl ^ (jr & 3);
    const int koff_sh = (hh * 64 + jloc) * 32 + s_src * 8;
    const unsigned voffK = (unsigned)(koff_sh * 2);
    const int kdst_off = hh * 2048 + tt * 8;   // shorts

    // ---- V staging (r10-verified pattern per 64-j subtile) ----
    const int sIdx = t >> 8;                   // which j-subtile this thread stages
    const int w4 = (t >> 6) & 3;
    const int vrow0 = w4 * 16 + (l >> 2);
    const int vchunk = l & 3;
    unsigned voffVb[4];
    int vdst[4][2];
    #pragma unroll
    for (int p = 0; p < 4; ++p) {
        const int row = vrow0 + p * 64;
        voffVb[p] = (unsigned)(((size_t)row * N_ + sIdx * 64 + vchunk * 16) * 2);
        const int s0 = vchunk * 2;
        vdst[p][0] = row * 128 + (((s0    ) ^ (row & 7)) << 4);
        vdst[p][1] = row * 128 + (((s0 + 1) ^ (row & 7)) << 4);
    }

    union PB { unsigned wo[4]; bf16x8 v8; };

    // ---- prologue: stage K(0), V(0) into buffer 0 ----
    {
        const bf16x8 k0 = *reinterpret_cast<const bf16x8*>(
            reinterpret_cast<const char*>(kb) + voffK);
        *reinterpret_cast<bf16x8*>(&kT[0][kdst_off]) = k0;
        #pragma unroll
        for (int p = 0; p < 4; ++p) {
            const char* src = reinterpret_cast<const char*>(vb) + voffVb[p];
            const bf16x8 a0 = *reinterpret_cast<const bf16x8*>(src);
            const bf16x8 a1 = *reinterpret_cast<const bf16x8*>(src + 16);
            char* vd = reinterpret_cast<char*>(&vT[0][sIdx][0]);
            *reinterpret_cast<bf16x8*>(vd + vdst[p][0]) = a0;
            *reinterpret_cast<bf16x8*>(vd + vdst[p][1]) = a1;
        }
    }
    __syncthreads();

    // ---- main loop: 32 iterations of 128 j, ONE barrier each ----
    for (int jj = 0; jj < 32; ++jj) {
        const int cur = jj & 1, nxt = cur ^ 1;
        const bool pf = (jj + 1 < 32);

        // issue next-tile staging loads (held in regs until bottom: T14)
        bf16x8 knx;
        bf16x8 vnx[4][2];
        if (pf) {
            const unsigned short* sbk = kb + (size_t)(jj + 1) * 128 * 32;
            asm volatile("global_load_dwordx4 %0, %1, %2"
                         : "=v"(knx) : "v"(voffK), "s"(sbk));
            const unsigned short* sbv = vb + (size_t)(jj + 1) * 128;
            #pragma unroll
            for (int p = 0; p < 4; ++p)
                asm volatile("global_load_dwordx4 %0, %2, %3\n\t"
                             "global_load_dwordx4 %1, %2, %3 offset:16"
                             : "=v"(vnx[p][0]), "=v"(vnx[p][1])
                             : "v"(voffVb[p]), "s"(sbv));
            __builtin_amdgcn_sched_barrier(0);
        }

        // ---- QK: 4 shared K reads (own j-half) -> 8 MFMA ----
        f32x4 sTA[4], sTB[4];
        {
            const char* kbuf = reinterpret_cast<const char*>(&kT[cur][0]) + JH * 4096;
            #pragma unroll
            for (int jt = 0; jt < 4; ++jt) {
                const int row = jt * 16 + li;
                const bf16x8 kA = *reinterpret_cast<const bf16x8*>(
                    kbuf + row * 64 + ((g ^ (row & 3)) << 4));
                sTA[jt] = __builtin_amdgcn_mfma_f32_16x16x32_bf16(kA, qfA, z4, 0, 0, 0);
                sTB[jt] = __builtin_amdgcn_mfma_f32_16x16x32_bf16(kA, qfB, z4, 0, 0, 0);
            }
        }

        // ---- softmax both groups (partial over own j-half) ----
        float mxA = fmaxf(fmaxf(fmaxf(sTA[0][0], sTA[0][1]), fmaxf(sTA[0][2], sTA[0][3])),
                          fmaxf(fmaxf(sTA[1][0], sTA[1][1]), fmaxf(sTA[1][2], sTA[1][3])));
        mxA = fmaxf(mxA, fmaxf(fmaxf(fmaxf(sTA[2][0], sTA[2][1]), fmaxf(sTA[2][2], sTA[2][3])),
                               fmaxf(fmaxf(sTA[3][0], sTA[3][1]), fmaxf(sTA[3][2], sTA[3][3]))));
        float mxB = fmaxf(fmaxf(fmaxf(sTB[0][0], sTB[0][1]), fmaxf(sTB[0][2], sTB[0][3])),
                          fmaxf(fmaxf(sTB[1][0], sTB[1][1]), fmaxf(sTB[1][2], sTB[1][3])));
        mxB = fmaxf(mxB, fmaxf(fmaxf(fmaxf(sTB[2][0], sTB[2][1]), fmaxf(sTB[2][2], sTB[2][3])),
                               fmaxf(fmaxf(sTB[3][0], sTB[3][1]), fmaxf(sTB[3][2], sTB[3][3]))));
        if (__any(fmaxf(mxA - m_runA, mxB - m_runB) > DEFER_THR)) {
            float mwA = fmaxf(mxA, __shfl_xor(mxA, 16));
            mwA = fmaxf(mwA, __shfl_xor(mwA, 32));
            float mwB = fmaxf(mxB, __shfl_xor(mxB, 16));
            mwB = fmaxf(mwB, __shfl_xor(mwB, 32));
            const float mnA = fmaxf(m_runA, mwA);
            const float mnB = fmaxf(m_runB, mwB);
            const float fA = __builtin_amdgcn_exp2f(m_runA - mnA);
            const float fB = __builtin_amdgcn_exp2f(m_runB - mnB);
            m_runA = mnA; m_runB = mnB;
            l_pA *= fA;   l_pB *= fB;
            #pragma unroll
            for (int ct = 0; ct < 16; ++ct) { accA[ct] *= fA; accB[ct] *= fB; }
        }
        #pragma unroll
        for (int jt = 0; jt < 4; ++jt)
            #pragma unroll
            for (int r = 0; r < 4; ++r) {
                sTA[jt][r] = __builtin_amdgcn_exp2f(sTA[jt][r] - m_runA);
                sTB[jt][r] = __builtin_amdgcn_exp2f(sTB[jt][r] - m_runB);
            }
        {
            const f32x4 svA = (sTA[0] + sTA[1]) + (sTA[2] + sTA[3]);
            const f32x4 svB = (sTB[0] + sTB[1]) + (sTB[2] + sTB[3]);
            l_pA += (svA[0] + svA[1]) + (svA[2] + svA[3]);
            l_pB += (svB[0] + svB[1]) + (svB[2] + svB[3]);
        }

        // ---- pack P into PV B-frags (in-lane, r3-verified mapping) ----
        PB pbA0, pbA1, pbB0, pbB1;
        pbA0.wo[0] = cvtpk(sTA[0][0], sTA[0][1]); pbA0.wo[1] = cvtpk(sTA[0][2], sTA[0][3]);
        pbA0.wo[2] = cvtpk(sTA[1][0], sTA[1][1]); pbA0.wo[3] = cvtpk(sTA[1][2], sTA[1][3]);
        pbA1.wo[0] = cvtpk(sTA[2][0], sTA[2][1]); pbA1.wo[1] = cvtpk(sTA[2][2], sTA[2][3]);
        pbA1.wo[2] = cvtpk(sTA[3][0], sTA[3][1]); pbA1.wo[3] = cvtpk(sTA[3][2], sTA[3][3]);
        pbB0.wo[0] = cvtpk(sTB[0][0], sTB[0][1]); pbB0.wo[1] = cvtpk(sTB[0][2], sTB[0][3]);
        pbB0.wo[2] = cvtpk(sTB[1][0], sTB[1][1]); pbB0.wo[3] = cvtpk(sTB[1][2], sTB[1][3]);
        pbB1.wo[0] = cvtpk(sTB[2][0], sTB[2][1]); pbB1.wo[1] = cvtpk(sTB[2][2], sTB[2][3]);
        pbB1.wo[2] = cvtpk(sTB[3][0], sTB[3][1]); pbB1.wo[3] = cvtpk(sTB[3][2], sTB[3][3]);

        // ---- PV: 32 shared V reads (own j-subtile) -> 64 MFMA ----
        __builtin_amdgcn_s_setprio(1);
        {
            const char* vbuf = reinterpret_cast<const char*>(&vT[cur][JH][0]);
            #pragma unroll
            for (int ct = 0; ct < 16; ++ct) {
                const int vrow = ct * 16 + li;
                const bf16x8 vA0 = *reinterpret_cast<const bf16x8*>(
                    vbuf + vrow * 128 + (((g    ) ^ (vrow & 7)) << 4));
                const bf16x8 vA1 = *reinterpret_cast<const bf16x8*>(
                    vbuf + vrow * 128 + (((4 + g) ^ (vrow & 7)) << 4));
                accA[ct] = __builtin_amdgcn_mfma_f32_16x16x32_bf16(vA0, pbA0.v8, accA[ct], 0, 0, 0);
                accB[ct] = __builtin_amdgcn_mfma_f32_16x16x32_bf16(vA0, pbB0.v8, accB[ct], 0, 0, 0);
                accA[ct] = __builtin_amdgcn_mfma_f32_16x16x32_bf16(vA1, pbA1.v8, accA[ct], 0, 0, 0);
                accB[ct] = __builtin_amdgcn_mfma_f32_16x16x32_bf16(vA1, pbB1.v8, accB[ct], 0, 0, 0);
            }
        }
        __builtin_amdgcn_s_setprio(0);

        // ---- write staged K/V to the other buffer ----
        if (pf) {
            asm volatile("s_waitcnt vmcnt(0)" ::: "memory");
            __builtin_amdgcn_sched_barrier(0);
            *reinterpret_cast<bf16x8*>(&kT[nxt][kdst_off]) = knx;
            char* vd = reinterpret_cast<char*>(&vT[nxt][sIdx][0]);
            #pragma unroll
            for (int p = 0; p < 4; ++p) {
                *reinterpret_cast<bf16x8*>(vd + vdst[p][0]) = vnx[p][0];
                *reinterpret_cast<bf16x8*>(vd + vdst[p][1]) = vnx[p][1];
            }
        }
        __syncthreads();
    }

    // ---- epilogue: merge the two j-halves per query slice ----
    // reduce l across g (lanes of same query)
    float lA = l_pA, lB = l_pB;
    lA += __shfl_xor(lA, 16); lA += __shfl_xor(lA, 32);
    lB += __shfl_xor(lB, 16); lB += __shfl_xor(lB, 32);

    // publish m/l partials
    if (l < 16) {
        m_x[QS][JH][0][li] = m_runA; m_x[QS][JH][1][li] = m_runB;
        l_x[QS][JH][0][li] = lA;     l_x[QS][JH][1][li] = lB;
    }

    // exchange O halves through the retired V buffer (128 KB)
    // wave keeps cts [JH*8, +8), writes cts [(1-JH)*8, +8) for its partner.
    f32x4* mrg = reinterpret_cast<f32x4*>(&vT[0][0][0]);
    const int woff = (1 - JH) * 8;
    #pragma unroll
    for (int c8 = 0; c8 < 8; ++c8) {
        mrg[((((QS * 2 + JH) * 2 + 0) * 8 + c8) << 6) + l] = accA[woff + c8];
        mrg[((((QS * 2 + JH) * 2 + 1) * 8 + c8) << 6) + l] = accB[woff + c8];
    }
    __syncthreads();

    // merge own kept half with partner's written half
    const int PJ = JH ^ 1;
    const float mpA = m_x[QS][PJ][0][li], mpB = m_x[QS][PJ][1][li];
    const float lqA = l_x[QS][PJ][0][li], lqB = l_x[QS][PJ][1][li];
    const float mMA = fmaxf(m_runA, mpA);
    const float mMB = fmaxf(m_runB, mpB);
    const float fsA = __builtin_amdgcn_exp2f(m_runA - mMA);
    const float fpA = __builtin_amdgcn_exp2f(mpA - mMA);
    const float fsB = __builtin_amdgcn_exp2f(m_runB - mMB);
    const float fpB = __builtin_amdgcn_exp2f(mpB - mMB);
    const float linvA = 1.0f / (lA * fsA + lqA * fpA);
    const float linvB = 1.0f / (lB * fsB + lqB * fpB);

    const float gm = gamma[0];
    const int iA = i0 + QS * 32 + li;
    const float* xb2 = x + ((size_t)b * C_) * N_;
    float* ob = out + ((size_t)b * C_) * N_;
    #pragma unroll
    for (int c8 = 0; c8 < 8; ++c8) {
        const int ct = JH * 8 + c8;
        const f32x4 oA = accA[ct] * fsA
            + mrg[((((QS * 2 + PJ) * 2 + 0) * 8 + c8) << 6) + l] * fpA;
        const f32x4 oB = accB[ct] * fsB
            + mrg[((((QS * 2 + PJ) * 2 + 1) * 8 + c8) << 6) + l] * fpB;
        #pragma unroll
        for (int r = 0; r < 4; ++r) {
            const int c = ct * 16 + 4 * g + r;
            const size_t off = (size_t)c * N_ + iA;
            ob[off]      = gm * oA[r] * linvA + xb2[off];
            ob[off + 16] = gm * oB[r] * linvB + xb2[off + 16];
        }
    }
}

// ---------------------------------------------------------------------------
// Workspace: q [8][4096][32] | k | v [8][256][4096] bf16 | wbf [320*256] bf16
// = 2 + 2 + 16 + 0.16 MB = ~20.2 MB in d_ws.
// ---------------------------------------------------------------------------
extern "C" void kernel_launch(void* const* d_in, const int* in_sizes, int n_in,
                              void* d_out, int out_size, void* d_ws, size_t ws_size,
                              hipStream_t stream) {
    const float* x     = (const float*)d_in[0];
    const float* Wq    = (const float*)d_in[1];
    const float* bq    = (const float*)d_in[2];
    const float* Wk    = (const float*)d_in[3];
    const float* bk    = (const float*)d_in[4];
    const float* Wv    = (const float*)d_in[5];
    const float* bv    = (const float*)d_in[6];
    const float* gamma = (const float*)d_in[7];
    float* out = (float*)d_out;

    unsigned short* q   = (unsigned short*)d_ws;
    unsigned short* k   = q + (size_t)B_ * N_ * 32;
    unsigned short* v   = k + (size_t)B_ * N_ * 32;
    unsigned short* wbf = v + (size_t)B_ * C_ * N_;

    dim3 grid(N_ / 64, B_);
    w_prep<<<80, 256, 0, stream>>>(Wq, Wk, Wv, wbf);
    qkv_proj_mfma<<<grid, 256, 0, stream>>>(x, wbf, bq, bk, bv, q, k, v);
    attn_mfma<<<256, 512, 0, stream>>>(q, k, v, x, gamma, out);
}

// Round 13
// 135.110 us; speedup vs baseline: 2.8673x; 2.8673x over previous
//
#include <hip/hip_runtime.h>
#include <hip/hip_bf16.h>
#include <math.h>

// Problem constants: x [8,256,64,64] fp32, N = 4096, C = 256, Cqk = 32.
#define B_   8
#define C_   256
#define N_   4096
// 1/sqrt(32) * log2(e): scores computed directly in log2 space -> exp2 only.
#define QSCALE_L2E 0.2550541451582815f
#define DEFER_THR  11.5f   // defer-max threshold in log2 units (~8 nats)

typedef __attribute__((ext_vector_type(8))) short bf16x8;   // 8 bf16 = 4 VGPRs
typedef __attribute__((ext_vector_type(4))) float f32x4;

__device__ __forceinline__ unsigned short bfu(float f) {
    __hip_bfloat16 h = __float2bfloat16(f);
    return __builtin_bit_cast(unsigned short, h);
}
// v_cvt_pk_bf16_f32: lo -> D[15:0], hi -> D[31:16] (single VALU op)
__device__ __forceinline__ unsigned cvtpk(float lo, float hi) {
    unsigned r;
    asm("v_cvt_pk_bf16_f32 %0, %1, %2" : "=v"(r) : "v"(lo), "v"(hi));
    return r;
}

// ---------------------------------------------------------------------------
// Kernel 0: one-time W -> bf16 prep. wbf layout: Wq[32*256] | Wk | Wv[256*256].
// ---------------------------------------------------------------------------
__global__ __launch_bounds__(256) void w_prep(
    const float* __restrict__ Wq, const float* __restrict__ Wk,
    const float* __restrict__ Wv, unsigned short* __restrict__ wbf)
{
    const int i = blockIdx.x * 256 + threadIdx.x;
    const int off = i * 4;
    float4 f;
    if (off < 32 * C_)            f = *reinterpret_cast<const float4*>(Wq + off);
    else if (off < 64 * C_)       f = *reinterpret_cast<const float4*>(Wk + off - 32 * C_);
    else                          f = *reinterpret_cast<const float4*>(Wv + off - 64 * C_);
    ushort4 u;
    u.x = bfu(f.x); u.y = bfu(f.y); u.z = bfu(f.z); u.w = bfu(f.w);
    *reinterpret_cast<ushort4*>(wbf + off) = u;
}

// ---------------------------------------------------------------------------
// Kernel 1: QKV projection via MFMA (unchanged since round 6).
// Outputs: q,k [b][n][32] bf16 (q pre-scaled by QSCALE_L2E), v [b][c][n] bf16.
// ---------------------------------------------------------------------------
__global__ __launch_bounds__(256, 2) void qkv_proj_mfma(
    const float* __restrict__ x, const unsigned short* __restrict__ wbf,
    const float* __restrict__ bq, const float* __restrict__ bk,
    const float* __restrict__ bv,
    unsigned short* __restrict__ q, unsigned short* __restrict__ k,
    unsigned short* __restrict__ v)
{
    const int b = blockIdx.y, n0 = blockIdx.x * 64;
    const int t = threadIdx.x;
    const int w = t >> 6, l = t & 63;
    const int li = l & 15, g = l >> 4;

    __shared__ unsigned short xT[64 * 256];     // 32 KB; reused as vS[256][64]
    __shared__ unsigned short qkS[2 * 64 * 32]; // 8 KB

    {
        const int n = t & 63;
        const int cq0 = t >> 6;
        const float* xb = x + ((size_t)b * C_) * N_ + n0 + n;
        #pragma unroll 4
        for (int s = 0; s < 16; ++s) {
            const int cq = cq0 + 4 * s;
            const float f0 = xb[(size_t)(cq * 4 + 0) * N_];
            const float f1 = xb[(size_t)(cq * 4 + 1) * N_];
            const float f2 = xb[(size_t)(cq * 4 + 2) * N_];
            const float f3 = xb[(size_t)(cq * 4 + 3) * N_];
            ushort4 pk;
            pk.x = bfu(f0); pk.y = bfu(f1); pk.z = bfu(f2); pk.w = bfu(f3);
            const int byte = n * 512 + (((cq >> 1) ^ (n & 7)) << 4) + (cq & 1) * 8;
            *reinterpret_cast<ushort4*>(reinterpret_cast<char*>(xT) + byte) = pk;
        }
    }
    __syncthreads();

    const unsigned short* wq_bf = wbf;
    const unsigned short* wk_bf = wbf + 32 * C_;
    const unsigned short* wv_bf = wbf + 64 * C_;

    const unsigned short* wqk_bf = (w < 2) ? wq_bf : wk_bf;
    const float* bqk = (w < 2) ? bq : bk;
    const float qscl = (w < 2) ? QSCALE_L2E : 1.0f;
    const int mt0 = (w & 1) * 2;
    const int ov0 = w * 64;

    f32x4 accv[4][4];
    f32x4 accq[2][2];
    const f32x4 z4 = {0.f, 0.f, 0.f, 0.f};
    #pragma unroll
    for (int a = 0; a < 4; ++a)
        #pragma unroll
        for (int c2 = 0; c2 < 4; ++c2) accv[a][c2] = z4;
    #pragma unroll
    for (int a = 0; a < 2; ++a)
        #pragma unroll
        for (int c2 = 0; c2 < 2; ++c2) accq[a][c2] = z4;

    #pragma unroll 2
    for (int kk = 0; kk < 8; ++kk) {
        bf16x8 xf[4];
        #pragma unroll
        for (int nt = 0; nt < 4; ++nt) {
            const int row = nt * 16 + li;
            const int byte = row * 512 + (((kk * 4 + g) ^ (row & 7)) << 4);
            xf[nt] = *reinterpret_cast<const bf16x8*>(
                reinterpret_cast<const char*>(xT) + byte);
        }
        #pragma unroll
        for (int ot = 0; ot < 4; ++ot) {
            const bf16x8 wV = *reinterpret_cast<const bf16x8*>(
                wv_bf + (size_t)(ov0 + ot * 16 + li) * C_ + kk * 32 + g * 8);
            #pragma unroll
            for (int nt = 0; nt < 4; ++nt)
                accv[nt][ot] = __builtin_amdgcn_mfma_f32_16x16x32_bf16(
                    xf[nt], wV, accv[nt][ot], 0, 0, 0);
        }
        #pragma unroll
        for (int ot = 0; ot < 2; ++ot) {
            const bf16x8 wA = *reinterpret_cast<const bf16x8*>(
                wqk_bf + (size_t)(ot * 16 + li) * C_ + kk * 32 + g * 8);
            #pragma unroll
            for (int m2 = 0; m2 < 2; ++m2)
                accq[ot][m2] = __builtin_amdgcn_mfma_f32_16x16x32_bf16(
                    wA, xf[mt0 + m2], accq[ot][m2], 0, 0, 0);
        }
    }

    __syncthreads();   // xT reads done: reuse as vS

    {
        const int qk = (w < 2) ? 0 : 1;
        #pragma unroll
        for (int ot = 0; ot < 2; ++ot) {
            const int d0 = ot * 16 + 4 * g;
            const float4 b4 = *reinterpret_cast<const float4*>(bqk + d0);
            const int slot = ot * 4 + g;
            #pragma unroll
            for (int m2 = 0; m2 < 2; ++m2) {
                const int n = (mt0 + m2) * 16 + li;
                ushort4 s4;
                s4.x = bfu((accq[ot][m2][0] + b4.x) * qscl);
                s4.y = bfu((accq[ot][m2][1] + b4.y) * qscl);
                s4.z = bfu((accq[ot][m2][2] + b4.z) * qscl);
                s4.w = bfu((accq[ot][m2][3] + b4.w) * qscl);
                const int byte = qk * 4096 + n * 64 + ((slot ^ (n & 7)) << 3);
                *reinterpret_cast<ushort4*>(reinterpret_cast<char*>(qkS) + byte) = s4;
            }
        }
    }
    {
        #pragma unroll
        for (int ot = 0; ot < 4; ++ot) {
            const int o = ov0 + ot * 16 + li;
            const float bias = bv[o];
            #pragma unroll
            for (int nt = 0; nt < 4; ++nt) {
                ushort4 s4;
                s4.x = bfu(accv[nt][ot][0] + bias);
                s4.y = bfu(accv[nt][ot][1] + bias);
                s4.z = bfu(accv[nt][ot][2] + bias);
                s4.w = bfu(accv[nt][ot][3] + bias);
                const int slot = nt * 4 + g;
                const int byte = o * 128 + ((slot ^ (o & 7)) << 3);
                *reinterpret_cast<ushort4*>(reinterpret_cast<char*>(xT) + byte) = s4;
            }
        }
    }
    __syncthreads();

    {
        const char* qks = reinterpret_cast<const char*>(qkS);
        #pragma unroll
        for (int qk = 0; qk < 2; ++qk) {
            const int n = t >> 2, s2 = (t & 3) * 2;
            const int byteA = qk * 4096 + n * 64 + (((s2    ) ^ (n & 7)) << 3);
            const int byteB = qk * 4096 + n * 64 + (((s2 + 1) ^ (n & 7)) << 3);
            const uint2 lo = *reinterpret_cast<const uint2*>(qks + byteA);
            const uint2 hi = *reinterpret_cast<const uint2*>(qks + byteB);
            uint4 val = make_uint4(lo.x, lo.y, hi.x, hi.y);
            unsigned short* dst = (qk == 0) ? q : k;
            *reinterpret_cast<uint4*>(dst + ((size_t)b * N_ + n0) * 32 + t * 8) = val;
        }
    }
    {
        const char* vs = reinterpret_cast<const char*>(xT);
        #pragma unroll
        for (int p2 = 0; p2 < 8; ++p2) {
            const int o = p2 * 32 + (t >> 3);
            const int s2 = (t & 7) * 2;
            const int byteA = o * 128 + (((s2    ) ^ (o & 7)) << 3);
            const int byteB = o * 128 + (((s2 + 1) ^ (o & 7)) << 3);
            const uint2 lo = *reinterpret_cast<const uint2*>(vs + byteA);
            const uint2 hi = *reinterpret_cast<const uint2*>(vs + byteB);
            uint4 val = make_uint4(lo.x, lo.y, hi.x, hi.y);
            *reinterpret_cast<uint4*>(v + ((size_t)b * C_ + o) * N_ + n0 + (t & 7) * 8) = val;
        }
    }
}

// ---------------------------------------------------------------------------
// Kernel 2: flash attention, 32 q/wave + j-split (round-12 structure) with
// the scratch bug fixed: ALL accumulator indices are compile-time constants
// (rule #20 — r12's runtime-indexed epilogue demoted acc[] to scratch:
// 2.2 GB HBM writes). Epilogue is duplicated per JH branch, static indices.
// grid 256 (b=id&7 XCD-local, i0=(id>>3)*128), 512 thr (8 waves), 1 block/CU.
// ---------------------------------------------------------------------------
__global__ __launch_bounds__(512, 2) void attn_mfma(
    const unsigned short* __restrict__ q, const unsigned short* __restrict__ k,
    const unsigned short* __restrict__ v,
    const float* __restrict__ x, const float* __restrict__ gamma,
    float* __restrict__ out)
{
    const int id = blockIdx.x;
    const int b = id & 7;                 // batch == XCD
    const int i0 = (id >> 3) * 128;
    const int t = threadIdx.x;
    const int w = t >> 6, l = t & 63;
    const int li = l & 15, g = l >> 4;
    const int QS = w & 3;                 // query slice: 32 queries
    const int JH = w >> 2;                // j-half of the 128-j tile

    __shared__ unsigned short kT[2][128 * 32];              // 16 KB dbuf K
    __shared__ __align__(16) unsigned short vT[2][2][256 * 64];  // 128 KB dbuf V
    __shared__ float m_x[4][2][2][16];                      // [qs][jh][grp][li]
    __shared__ float l_x[4][2][2][16];

    const unsigned short* qb = q + (size_t)b * N_ * 32;
    const unsigned short* kb = k + (size_t)b * N_ * 32;
    const unsigned short* vb = v + ((size_t)b * C_) * N_;

    // Q B-frags for own 32 queries: group A = i0+QS*32+li, group B = A+16
    const bf16x8 qfA = *reinterpret_cast<const bf16x8*>(
        qb + (size_t)(i0 + QS * 32 + li) * 32 + g * 8);
    const bf16x8 qfB = *reinterpret_cast<const bf16x8*>(
        qb + (size_t)(i0 + QS * 32 + 16 + li) * 32 + g * 8);

    f32x4 accA[16], accB[16];   // O^T partial (own j-half): c = ct*16+4g+r
    const f32x4 z4 = {0.f, 0.f, 0.f, 0.f};
    #pragma unroll
    for (int a = 0; a < 16; ++a) { accA[a] = z4; accB[a] = z4; }

    float m_runA = -3.0e38f, m_runB = -3.0e38f;
    float l_pA = 0.f, l_pB = 0.f;

    // ---- K staging (128-row tile): tt within 256, hh = 64-row half ----
    const int tt = t & 255, hh = t >> 8;
    const int jr = tt >> 2, sl = tt & 3;
    const int jt_s = jr >> 4, gg = (jr >> 2) & 3, rr = jr & 3;
    const int jloc = (jt_s >> 1) * 32 + (jt_s & 1) * 4 + gg * 8 + rr;
    const int s_src = sl ^ (jr & 3);
    const int koff_sh = (hh * 64 + jloc) * 32 + s_src * 8;
    const unsigned voffK = (unsigned)(koff_sh * 2);
    const int kdst_off = hh * 2048 + tt * 8;   // shorts

    // ---- V staging (per 64-j subtile, r10-verified) ----
    const int sIdx = t >> 8;                   // which j-subtile this thread stages
    const int w4 = (t >> 6) & 3;
    const int vrow0 = w4 * 16 + (l >> 2);
    const int vchunk = l & 3;
    unsigned voffVb[4];
    int vdst[4][2];
    #pragma unroll
    for (int p = 0; p < 4; ++p) {
        const int row = vrow0 + p * 64;
        voffVb[p] = (unsigned)(((size_t)row * N_ + sIdx * 64 + vchunk * 16) * 2);
        const int s0 = vchunk * 2;
        vdst[p][0] = row * 128 + (((s0    ) ^ (row & 7)) << 4);
        vdst[p][1] = row * 128 + (((s0 + 1) ^ (row & 7)) << 4);
    }

    union PB { unsigned wo[4]; bf16x8 v8; };

    // ---- prologue: stage K(0), V(0) into buffer 0 ----
    {
        const bf16x8 k0 = *reinterpret_cast<const bf16x8*>(
            reinterpret_cast<const char*>(kb) + voffK);
        *reinterpret_cast<bf16x8*>(&kT[0][kdst_off]) = k0;
        #pragma unroll
        for (int p = 0; p < 4; ++p) {
            const char* src = reinterpret_cast<const char*>(vb) + voffVb[p];
            const bf16x8 a0 = *reinterpret_cast<const bf16x8*>(src);
            const bf16x8 a1 = *reinterpret_cast<const bf16x8*>(src + 16);
            char* vd = reinterpret_cast<char*>(&vT[0][sIdx][0]);
            *reinterpret_cast<bf16x8*>(vd + vdst[p][0]) = a0;
            *reinterpret_cast<bf16x8*>(vd + vdst[p][1]) = a1;
        }
    }
    __syncthreads();

    // ---- main loop: 32 iterations of 128 j, ONE barrier each ----
    for (int jj = 0; jj < 32; ++jj) {
        const int cur = jj & 1, nxt = cur ^ 1;
        const bool pf = (jj + 1 < 32);

        // issue next-tile staging loads (held in regs until bottom: T14)
        bf16x8 knx;
        bf16x8 vnx[4][2];
        if (pf) {
            const unsigned short* sbk = kb + (size_t)(jj + 1) * 128 * 32;
            asm volatile("global_load_dwordx4 %0, %1, %2"
                         : "=v"(knx) : "v"(voffK), "s"(sbk));
            const unsigned short* sbv = vb + (size_t)(jj + 1) * 128;
            #pragma unroll
            for (int p = 0; p < 4; ++p)
                asm volatile("global_load_dwordx4 %0, %2, %3\n\t"
                             "global_load_dwordx4 %1, %2, %3 offset:16"
                             : "=v"(vnx[p][0]), "=v"(vnx[p][1])
                             : "v"(voffVb[p]), "s"(sbv));
            __builtin_amdgcn_sched_barrier(0);
        }

        // ---- QK: 4 shared K reads (own j-half) -> 8 MFMA ----
        f32x4 sTA[4], sTB[4];
        {
            const char* kbuf = reinterpret_cast<const char*>(&kT[cur][0]) + JH * 4096;
            #pragma unroll
            for (int jt = 0; jt < 4; ++jt) {
                const int row = jt * 16 + li;
                const bf16x8 kA = *reinterpret_cast<const bf16x8*>(
                    kbuf + row * 64 + ((g ^ (row & 3)) << 4));
                sTA[jt] = __builtin_amdgcn_mfma_f32_16x16x32_bf16(kA, qfA, z4, 0, 0, 0);
                sTB[jt] = __builtin_amdgcn_mfma_f32_16x16x32_bf16(kA, qfB, z4, 0, 0, 0);
            }
        }

        // ---- softmax both groups (partial over own j-half) ----
        float mxA = fmaxf(fmaxf(fmaxf(sTA[0][0], sTA[0][1]), fmaxf(sTA[0][2], sTA[0][3])),
                          fmaxf(fmaxf(sTA[1][0], sTA[1][1]), fmaxf(sTA[1][2], sTA[1][3])));
        mxA = fmaxf(mxA, fmaxf(fmaxf(fmaxf(sTA[2][0], sTA[2][1]), fmaxf(sTA[2][2], sTA[2][3])),
                               fmaxf(fmaxf(sTA[3][0], sTA[3][1]), fmaxf(sTA[3][2], sTA[3][3]))));
        float mxB = fmaxf(fmaxf(fmaxf(sTB[0][0], sTB[0][1]), fmaxf(sTB[0][2], sTB[0][3])),
                          fmaxf(fmaxf(sTB[1][0], sTB[1][1]), fmaxf(sTB[1][2], sTB[1][3])));
        mxB = fmaxf(mxB, fmaxf(fmaxf(fmaxf(sTB[2][0], sTB[2][1]), fmaxf(sTB[2][2], sTB[2][3])),
                               fmaxf(fmaxf(sTB[3][0], sTB[3][1]), fmaxf(sTB[3][2], sTB[3][3]))));
        if (__any(fmaxf(mxA - m_runA, mxB - m_runB) > DEFER_THR)) {
            float mwA = fmaxf(mxA, __shfl_xor(mxA, 16));
            mwA = fmaxf(mwA, __shfl_xor(mwA, 32));
            float mwB = fmaxf(mxB, __shfl_xor(mxB, 16));
            mwB = fmaxf(mwB, __shfl_xor(mwB, 32));
            const float mnA = fmaxf(m_runA, mwA);
            const float mnB = fmaxf(m_runB, mwB);
            const float fA = __builtin_amdgcn_exp2f(m_runA - mnA);
            const float fB = __builtin_amdgcn_exp2f(m_runB - mnB);
            m_runA = mnA; m_runB = mnB;
            l_pA *= fA;   l_pB *= fB;
            #pragma unroll
            for (int ct = 0; ct < 16; ++ct) { accA[ct] *= fA; accB[ct] *= fB; }
        }
        #pragma unroll
        for (int jt = 0; jt < 4; ++jt)
            #pragma unroll
            for (int r = 0; r < 4; ++r) {
                sTA[jt][r] = __builtin_amdgcn_exp2f(sTA[jt][r] - m_runA);
                sTB[jt][r] = __builtin_amdgcn_exp2f(sTB[jt][r] - m_runB);
            }
        {
            const f32x4 svA = (sTA[0] + sTA[1]) + (sTA[2] + sTA[3]);
            const f32x4 svB = (sTB[0] + sTB[1]) + (sTB[2] + sTB[3]);
            l_pA += (svA[0] + svA[1]) + (svA[2] + svA[3]);
            l_pB += (svB[0] + svB[1]) + (svB[2] + svB[3]);
        }

        // ---- pack P into PV B-frags (in-lane, r3-verified mapping) ----
        PB pbA0, pbA1, pbB0, pbB1;
        pbA0.wo[0] = cvtpk(sTA[0][0], sTA[0][1]); pbA0.wo[1] = cvtpk(sTA[0][2], sTA[0][3]);
        pbA0.wo[2] = cvtpk(sTA[1][0], sTA[1][1]); pbA0.wo[3] = cvtpk(sTA[1][2], sTA[1][3]);
        pbA1.wo[0] = cvtpk(sTA[2][0], sTA[2][1]); pbA1.wo[1] = cvtpk(sTA[2][2], sTA[2][3]);
        pbA1.wo[2] = cvtpk(sTA[3][0], sTA[3][1]); pbA1.wo[3] = cvtpk(sTA[3][2], sTA[3][3]);
        pbB0.wo[0] = cvtpk(sTB[0][0], sTB[0][1]); pbB0.wo[1] = cvtpk(sTB[0][2], sTB[0][3]);
        pbB0.wo[2] = cvtpk(sTB[1][0], sTB[1][1]); pbB0.wo[3] = cvtpk(sTB[1][2], sTB[1][3]);
        pbB1.wo[0] = cvtpk(sTB[2][0], sTB[2][1]); pbB1.wo[1] = cvtpk(sTB[2][2], sTB[2][3]);
        pbB1.wo[2] = cvtpk(sTB[3][0], sTB[3][1]); pbB1.wo[3] = cvtpk(sTB[3][2], sTB[3][3]);

        // ---- PV: 32 shared V reads (own j-subtile) -> 64 MFMA ----
        __builtin_amdgcn_s_setprio(1);
        {
            const char* vbuf = reinterpret_cast<const char*>(&vT[cur][JH][0]);
            #pragma unroll
            for (int ct = 0; ct < 16; ++ct) {
                const int vrow = ct * 16 + li;
                const bf16x8 vA0 = *reinterpret_cast<const bf16x8*>(
                    vbuf + vrow * 128 + (((g    ) ^ (vrow & 7)) << 4));
                const bf16x8 vA1 = *reinterpret_cast<const bf16x8*>(
                    vbuf + vrow * 128 + (((4 + g) ^ (vrow & 7)) << 4));
                accA[ct] = __builtin_amdgcn_mfma_f32_16x16x32_bf16(vA0, pbA0.v8, accA[ct], 0, 0, 0);
                accB[ct] = __builtin_amdgcn_mfma_f32_16x16x32_bf16(vA0, pbB0.v8, accB[ct], 0, 0, 0);
                accA[ct] = __builtin_amdgcn_mfma_f32_16x16x32_bf16(vA1, pbA1.v8, accA[ct], 0, 0, 0);
                accB[ct] = __builtin_amdgcn_mfma_f32_16x16x32_bf16(vA1, pbB1.v8, accB[ct], 0, 0, 0);
            }
        }
        __builtin_amdgcn_s_setprio(0);

        // ---- write staged K/V to the other buffer ----
        if (pf) {
            asm volatile("s_waitcnt vmcnt(0)" ::: "memory");
            __builtin_amdgcn_sched_barrier(0);
            *reinterpret_cast<bf16x8*>(&kT[nxt][kdst_off]) = knx;
            char* vd = reinterpret_cast<char*>(&vT[nxt][sIdx][0]);
            #pragma unroll
            for (int p = 0; p < 4; ++p) {
                *reinterpret_cast<bf16x8*>(vd + vdst[p][0]) = vnx[p][0];
                *reinterpret_cast<bf16x8*>(vd + vdst[p][1]) = vnx[p][1];
            }
        }
        __syncthreads();
    }

    // ---- epilogue: merge the two j-halves. ALL acc indices STATIC ----
    float lA = l_pA, lB = l_pB;
    lA += __shfl_xor(lA, 16); lA += __shfl_xor(lA, 32);
    lB += __shfl_xor(lB, 16); lB += __shfl_xor(lB, 32);

    if (l < 16) {
        m_x[QS][JH][0][li] = m_runA; m_x[QS][JH][1][li] = m_runB;
        l_x[QS][JH][0][li] = lA;     l_x[QS][JH][1][li] = lB;
    }

    // exchange O halves through the retired V buffer (64 KB of vT[0]).
    // wave keeps cts [JH*8,+8), writes cts [(1-JH)*8,+8) for its partner.
    f32x4* mrg = reinterpret_cast<f32x4*>(&vT[0][0][0]);
    if (JH == 0) {
        #pragma unroll
        for (int c8 = 0; c8 < 8; ++c8) {
            mrg[((((QS * 2 + 0) * 2 + 0) * 8 + c8) << 6) + l] = accA[8 + c8];
            mrg[((((QS * 2 + 0) * 2 + 1) * 8 + c8) << 6) + l] = accB[8 + c8];
        }
    } else {
        #pragma unroll
        for (int c8 = 0; c8 < 8; ++c8) {
            mrg[((((QS * 2 + 1) * 2 + 0) * 8 + c8) << 6) + l] = accA[c8];
            mrg[((((QS * 2 + 1) * 2 + 1) * 8 + c8) << 6) + l] = accB[c8];
        }
    }
    __syncthreads();

    // merge own kept half with partner's written half
    const int PJ = JH ^ 1;
    const float mpA = m_x[QS][PJ][0][li], mpB = m_x[QS][PJ][1][li];
    const float lqA = l_x[QS][PJ][0][li], lqB = l_x[QS][PJ][1][li];
    const float mMA = fmaxf(m_runA, mpA);
    const float mMB = fmaxf(m_runB, mpB);
    const float fsA = __builtin_amdgcn_exp2f(m_runA - mMA);
    const float fpA = __builtin_amdgcn_exp2f(mpA - mMA);
    const float fsB = __builtin_amdgcn_exp2f(m_runB - mMB);
    const float fpB = __builtin_amdgcn_exp2f(mpB - mMB);
    const float linvA = 1.0f / (lA * fsA + lqA * fpA);
    const float linvB = 1.0f / (lB * fsB + lqB * fpB);

    const float gm = gamma[0];
    const int iA = i0 + QS * 32 + li;
    const float* xb2 = x + ((size_t)b * C_) * N_;
    float* ob = out + ((size_t)b * C_) * N_;
    if (JH == 0) {
        #pragma unroll
        for (int c8 = 0; c8 < 8; ++c8) {
            const f32x4 oA = accA[c8] * fsA
                + mrg[((((QS * 2 + 1) * 2 + 0) * 8 + c8) << 6) + l] * fpA;
            const f32x4 oB = accB[c8] * fsB
                + mrg[((((QS * 2 + 1) * 2 + 1) * 8 + c8) << 6) + l] * fpB;
            #pragma unroll
            for (int r = 0; r < 4; ++r) {
                const int c = c8 * 16 + 4 * g + r;
                const size_t off = (size_t)c * N_ + iA;
                ob[off]      = gm * oA[r] * linvA + xb2[off];
                ob[off + 16] = gm * oB[r] * linvB + xb2[off + 16];
            }
        }
    } else {
        #pragma unroll
        for (int c8 = 0; c8 < 8; ++c8) {
            const f32x4 oA = accA[8 + c8] * fsA
                + mrg[((((QS * 2 + 0) * 2 + 0) * 8 + c8) << 6) + l] * fpA;
            const f32x4 oB = accB[8 + c8] * fsB
                + mrg[((((QS * 2 + 0) * 2 + 1) * 8 + c8) << 6) + l] * fpB;
            #pragma unroll
            for (int r = 0; r < 4; ++r) {
                const int c = (8 + c8) * 16 + 4 * g + r;
                const size_t off = (size_t)c * N_ + iA;
                ob[off]      = gm * oA[r] * linvA + xb2[off];
                ob[off + 16] = gm * oB[r] * linvB + xb2[off + 16];
            }
        }
    }
}

// ---------------------------------------------------------------------------
// Workspace: q [8][4096][32] | k | v [8][256][4096] bf16 | wbf [320*256] bf16
// = 2 + 2 + 16 + 0.16 MB = ~20.2 MB in d_ws.
// ---------------------------------------------------------------------------
extern "C" void kernel_launch(void* const* d_in, const int* in_sizes, int n_in,
                              void* d_out, int out_size, void* d_ws, size_t ws_size,
                              hipStream_t stream) {
    const float* x     = (const float*)d_in[0];
    const float* Wq    = (const float*)d_in[1];
    const float* bq    = (const float*)d_in[2];
    const float* Wk    = (const float*)d_in[3];
    const float* bk    = (const float*)d_in[4];
    const float* Wv    = (const float*)d_in[5];
    const float* bv    = (const float*)d_in[6];
    const float* gamma = (const float*)d_in[7];
    float* out = (float*)d_out;

    unsigned short* q   = (unsigned short*)d_ws;
    unsigned short* k   = q + (size_t)B_ * N_ * 32;
    unsigned short* v   = k + (size_t)B_ * N_ * 32;
    unsigned short* wbf = v + (size_t)B_ * C_ * N_;

    dim3 grid(N_ / 64, B_);
    w_prep<<<80, 256, 0, stream>>>(Wq, Wk, Wv, wbf);
    qkv_proj_mfma<<<grid, 256, 0, stream>>>(x, wbf, bq, bk, bv, q, k, v);
    attn_mfma<<<256, 512, 0, stream>>>(q, k, v, x, gamma, out);
}